// Round 1
// baseline (123.114 us; speedup 1.0000x reference)
//
#include <hip/hip_runtime.h>
#include <hip/hip_bf16.h>

#define B_   64
#define N_   256
#define P_   12
#define D_   128
#define BN_  (B_*N_)      // 16384
#define EPSV 1e-5f

typedef float  f32x4  __attribute__((ext_vector_type(4)));
typedef __bf16 bf16x8 __attribute__((ext_vector_type(8)));
typedef __bf16 bf16x4 __attribute__((ext_vector_type(4)));

// module-scope scratch (fully rewritten every launch -> deterministic)
__device__ float g_avg[768*256];     // [b*12+p][n]  mean over d
__device__ float g_mx [768*256];     // [b*12+p][n]  max over d
__device__ float g_h1 [1536*128];    // rows 0..767 avg-branch, 768..1535 max-branch
__device__ float g_pool[BN_*P_];     // [bn][p] = sig(avg)+sig(max)

__device__ inline float sigm_(float x) { return 1.0f / (1.0f + __expf(-x)); }

__device__ inline float dot4_(float4 a, float4 b, float acc) {
  acc = fmaf(a.x, b.x, acc); acc = fmaf(a.y, b.y, acc);
  acc = fmaf(a.z, b.z, acc); acc = fmaf(a.w, b.w, acc);
  return acc;
}

// ---------------- K1: mean/max over d, one wave per (b,n) -------------------
__global__ __launch_bounds__(256) void k1_pool(const float* __restrict__ x) {
  int w = threadIdx.x >> 6, l = threadIdx.x & 63;
  int bn = blockIdx.x * 4 + w;
  const float* xp = x + (size_t)bn * (P_ * D_);
  int b = bn >> 8, n = bn & 255;
  float sacc[P_], macc[P_];
#pragma unroll
  for (int p = 0; p < P_; ++p) {
    float2 v = *(const float2*)(xp + p * D_ + 2 * l);
    float s = v.x + v.y;
    float m = fmaxf(v.x, v.y);
#pragma unroll
    for (int off = 32; off; off >>= 1) {
      s += __shfl_xor(s, off);
      m = fmaxf(m, __shfl_xor(m, off));
    }
    sacc[p] = s * (1.0f / D_);
    macc[p] = m;
  }
  if (l == 0) {
#pragma unroll
    for (int p = 0; p < P_; ++p) {
      g_avg[(b * P_ + p) * N_ + n] = sacc[p];
      g_mx [(b * P_ + p) * N_ + n] = macc[p];
    }
  }
}

// ---------------- K2a: layer1 (256->128) + exact GELU -----------------------
// rows 0..1535 (avg rows then max rows), cols 128. grid = 96*2 = 192 blocks.
__global__ __launch_bounds__(256) void k2_l1(const float* __restrict__ w_avg1,
                                             const float* __restrict__ w_max1) {
  __shared__ float in_t[16 * 256];
  __shared__ float w_t[64 * 68];
  int t = threadIdx.x;
  int rblk = blockIdx.x % 96, cblk = blockIdx.x / 96;
  int rr0 = rblk * 16, c0 = cblk * 64;
  bool mxb = (rr0 >= 768);
  int r768 = mxb ? rr0 - 768 : rr0;
  const float* in = (mxb ? g_mx : g_avg) + (size_t)r768 * 256;
  const float* w1 = mxb ? w_max1 : w_avg1;
#pragma unroll
  for (int i = 0; i < 4; ++i) {              // 1024 float4: 16 rows x 64
    int F = t + i * 256, r = F >> 6, k4 = F & 63;
    *(float4*)(in_t + r * 256 + k4 * 4) = *(const float4*)(in + r * 256 + k4 * 4);
  }
  int c = t & 63, rq = t >> 6;
  float a0 = 0, a1 = 0, a2 = 0, a3 = 0;
  for (int kc = 0; kc < 4; ++kc) {
    __syncthreads();
#pragma unroll
    for (int i = 0; i < 4; ++i) {            // 1024 float4: 64 rows x 16
      int F = t + i * 256, cr = F >> 4, k4 = F & 15;
      *(float4*)(w_t + cr * 68 + k4 * 4) =
          *(const float4*)(w1 + (size_t)(c0 + cr) * 256 + kc * 64 + k4 * 4);
    }
    __syncthreads();
#pragma unroll
    for (int k4 = 0; k4 < 16; ++k4) {
      float4 wv4 = *(float4*)(w_t + c * 68 + k4 * 4);
      a0 = dot4_(*(float4*)(in_t + (rq * 4 + 0) * 256 + kc * 64 + k4 * 4), wv4, a0);
      a1 = dot4_(*(float4*)(in_t + (rq * 4 + 1) * 256 + kc * 64 + k4 * 4), wv4, a1);
      a2 = dot4_(*(float4*)(in_t + (rq * 4 + 2) * 256 + kc * 64 + k4 * 4), wv4, a2);
      a3 = dot4_(*(float4*)(in_t + (rq * 4 + 3) * 256 + kc * 64 + k4 * 4), wv4, a3);
    }
  }
  float accs[4] = {a0, a1, a2, a3};
#pragma unroll
  for (int r = 0; r < 4; ++r) {
    float a = accs[r];
    float g = 0.5f * a * (1.0f + erff(a * 0.70710678f));
    g_h1[(size_t)(rr0 + rq * 4 + r) * 128 + c0 + c] = g;
  }
}

// ---------------- K2b: layer2 (128->256), sigmoid, branch-sum ---------------
// rows 768 (b,p), cols 256 (n). grid = 48*4 = 192 blocks.
__global__ __launch_bounds__(256) void k2_l2(const float* __restrict__ w_avg2,
                                             const float* __restrict__ w_max2) {
  __shared__ float ina_t[16 * 128];
  __shared__ float inm_t[16 * 128];
  __shared__ float wa_t[64 * 68];
  __shared__ float wm_t[64 * 68];
  int t = threadIdx.x;
  int rblk = blockIdx.x % 48, cblk = blockIdx.x / 48;
  int rr0 = rblk * 16, n0 = cblk * 64;
#pragma unroll
  for (int i = 0; i < 2; ++i) {              // 512 float4: 16 rows x 32
    int F = t + i * 256, r = F >> 5, k4 = F & 31;
    *(float4*)(ina_t + r * 128 + k4 * 4) = *(const float4*)(g_h1 + (size_t)(rr0 + r) * 128 + k4 * 4);
    *(float4*)(inm_t + r * 128 + k4 * 4) = *(const float4*)(g_h1 + (size_t)(768 + rr0 + r) * 128 + k4 * 4);
  }
  int c = t & 63, rq = t >> 6;
  float aa0=0, aa1=0, aa2=0, aa3=0, am0=0, am1=0, am2=0, am3=0;
  for (int kc = 0; kc < 2; ++kc) {
    __syncthreads();
#pragma unroll
    for (int i = 0; i < 4; ++i) {            // 1024 float4: 64 rows x 16
      int F = t + i * 256, cr = F >> 4, k4 = F & 15;
      *(float4*)(wa_t + cr * 68 + k4 * 4) =
          *(const float4*)(w_avg2 + (size_t)(n0 + cr) * 128 + kc * 64 + k4 * 4);
      *(float4*)(wm_t + cr * 68 + k4 * 4) =
          *(const float4*)(w_max2 + (size_t)(n0 + cr) * 128 + kc * 64 + k4 * 4);
    }
    __syncthreads();
#pragma unroll
    for (int k4 = 0; k4 < 16; ++k4) {
      float4 wa4 = *(float4*)(wa_t + c * 68 + k4 * 4);
      float4 wm4 = *(float4*)(wm_t + c * 68 + k4 * 4);
      float4 i0 = *(float4*)(ina_t + (rq * 4 + 0) * 128 + kc * 64 + k4 * 4);
      float4 i1 = *(float4*)(ina_t + (rq * 4 + 1) * 128 + kc * 64 + k4 * 4);
      float4 i2 = *(float4*)(ina_t + (rq * 4 + 2) * 128 + kc * 64 + k4 * 4);
      float4 i3 = *(float4*)(ina_t + (rq * 4 + 3) * 128 + kc * 64 + k4 * 4);
      aa0 = dot4_(i0, wa4, aa0); aa1 = dot4_(i1, wa4, aa1);
      aa2 = dot4_(i2, wa4, aa2); aa3 = dot4_(i3, wa4, aa3);
      float4 j0 = *(float4*)(inm_t + (rq * 4 + 0) * 128 + kc * 64 + k4 * 4);
      float4 j1 = *(float4*)(inm_t + (rq * 4 + 1) * 128 + kc * 64 + k4 * 4);
      float4 j2 = *(float4*)(inm_t + (rq * 4 + 2) * 128 + kc * 64 + k4 * 4);
      float4 j3 = *(float4*)(inm_t + (rq * 4 + 3) * 128 + kc * 64 + k4 * 4);
      am0 = dot4_(j0, wm4, am0); am1 = dot4_(j1, wm4, am1);
      am2 = dot4_(j2, wm4, am2); am3 = dot4_(j3, wm4, am3);
    }
  }
  float va[4] = {aa0, aa1, aa2, aa3};
  float vm[4] = {am0, am1, am2, am3};
#pragma unroll
  for (int r = 0; r < 4; ++r) {
    int rr = rr0 + rq * 4 + r;
    int b = rr / 12, p = rr % 12;
    float pv = sigm_(va[r]) + sigm_(vm[r]);
    g_pool[((size_t)b * 256 + (n0 + c)) * 12 + p] = pv;
  }
}

// ---------------- K3: fused main (k, v via MFMA, y, y_pool, out) ------------
// grid = 1024 blocks x 256 thr; each wave handles 4 bn sequentially.
__global__ __launch_bounds__(256) void k3_main(
    const float* __restrict__ x,  const float* __restrict__ wk,
    const float* __restrict__ kg, const float* __restrict__ kb,
    const float* __restrict__ krm, const float* __restrict__ krv,
    const float* __restrict__ wv,
    const float* __restrict__ vg, const float* __restrict__ vb,
    const float* __restrict__ vrm, const float* __restrict__ vrv,
    float* __restrict__ out) {
  __shared__ __align__(16) __bf16 wv_lds[128 * 128];  // [e][d] bf16, *sv[e], XOR-swizzled
  __shared__ float sv_l[128], tv_l[128];
  __shared__ float v_l[4][12 * 128];

  int t = threadIdx.x, w = t >> 6, l = t & 63;
  if (t < 128) {
    float s = vg[t] * rsqrtf(vrv[t] + EPSV);
    sv_l[t] = s;
    tv_l[t] = vb[t] - vrm[t] * s;
  }
  __syncthreads();
  {
    int e = t >> 1, dh = (t & 1) * 64;
    float s = sv_l[e];
    int swz = (e & 7) << 4;
#pragma unroll
    for (int i = 0; i < 16; ++i) {
      float4 v4 = *(const float4*)(wv + (size_t)e * 128 + dh + i * 4);
      bf16x4 h;
      h[0] = (__bf16)(v4.x * s); h[1] = (__bf16)(v4.y * s);
      h[2] = (__bf16)(v4.z * s); h[3] = (__bf16)(v4.w * s);
      int byte = (e * 256 + (dh + i * 4) * 2) ^ swz;
      *(bf16x4*)((char*)wv_lds + byte) = h;
    }
  }
  float ksc = kg[0] * rsqrtf(krv[0] + EPSV);
  float kbs = kb[0] - krm[0] * ksc;
  __syncthreads();

  int arow = (l & 15) > 11 ? 11 : (l & 15);  // clamp pad rows (garbage -> unused C rows)
  int ak = (l >> 4) * 8;
  int bcol = l & 15;
  int bko = (l >> 4) * 16;

  for (int it = 0; it < 4; ++it) {
    int bn = blockIdx.x * 16 + it * 4 + w;
    const float* xp = x + (size_t)bn * (P_ * D_);

    // A fragments: fp32 global -> bf16, 8 contiguous k per lane
    bf16x8 afr[4];
#pragma unroll
    for (int ks = 0; ks < 4; ++ks) {
      const float* src = xp + arow * 128 + ks * 32 + ak;
      float4 lo = *(const float4*)(src);
      float4 hi = *(const float4*)(src + 4);
      bf16x8 a;
      a[0] = (__bf16)lo.x; a[1] = (__bf16)lo.y; a[2] = (__bf16)lo.z; a[3] = (__bf16)lo.w;
      a[4] = (__bf16)hi.x; a[5] = (__bf16)hi.y; a[6] = (__bf16)hi.z; a[7] = (__bf16)hi.w;
      afr[ks] = a;
    }

    // k branch: k_raw over p, BN(1ch), SiLU, softmax over d (2 elems/lane)
    float kr0 = 0, kr1 = 0;
#pragma unroll
    for (int p = 0; p < P_; ++p) {
      float2 xv = *(const float2*)(xp + p * 128 + 2 * l);
      float wkp = wk[p];
      kr0 = fmaf(xv.x, wkp, kr0);
      kr1 = fmaf(xv.y, wkp, kr1);
    }
    float z0 = kr0 * ksc + kbs, z1 = kr1 * ksc + kbs;
    z0 = z0 * sigm_(z0);
    z1 = z1 * sigm_(z1);
    float mmax = fmaxf(z0, z1);
#pragma unroll
    for (int off = 32; off; off >>= 1) mmax = fmaxf(mmax, __shfl_xor(mmax, off));
    float e0 = __expf(z0 - mmax), e1 = __expf(z1 - mmax);
    float es = e0 + e1;
#pragma unroll
    for (int off = 32; off; off >>= 1) es += __shfl_xor(es, off);
    float inv = 1.0f / es;
    float k0 = e0 * inv, k1 = e1 * inv;

    // v_raw = xf @ (wv*sv)^T via MFMA 16x16x32 bf16
    f32x4 acc[8];
#pragma unroll
    for (int nt = 0; nt < 8; ++nt) acc[nt] = (f32x4){0.f, 0.f, 0.f, 0.f};
#pragma unroll
    for (int nt = 0; nt < 8; ++nt) {
      int er = bcol + nt * 16;
      int base = er * 256;
      int sw = (er & 7) << 4;
#pragma unroll
      for (int ks = 0; ks < 4; ++ks) {
        int byte = (base + ks * 64 + bko) ^ sw;
        bf16x8 bfr = *(const bf16x8*)((const char*)wv_lds + byte);
        acc[nt] = __builtin_amdgcn_mfma_f32_16x16x32_bf16(afr[ks], bfr, acc[nt], 0, 0, 0);
      }
    }

    // epilogue: + tv[e], SiLU, stash v tile in LDS (rows 12..15 dropped)
    int p0 = (l >> 4) * 4;
    if (p0 < 12) {
#pragma unroll
      for (int nt = 0; nt < 8; ++nt) {
        int e = bcol + nt * 16;
        float tvv = tv_l[e];
#pragma unroll
        for (int r = 0; r < 4; ++r) {
          float a = acc[nt][r] + tvv;
          float v = a * sigm_(a);
          v_l[w][(p0 + r) * 128 + e] = v;
        }
      }
    }
    __syncthreads();

    // y[p] = sum_e v*k ; y_pool[e] = sum_p pool*v ; out = y_pool (x) y
    const float* pp = g_pool + (size_t)bn * 12;
    float pl[P_];
#pragma unroll
    for (int p = 0; p < P_; ++p) pl[p] = pp[p];
    float yp0 = 0, yp1 = 0;
    float ypart[P_];
#pragma unroll
    for (int p = 0; p < P_; ++p) {
      float2 vvp = *(const float2*)(&v_l[w][0] + p * 128 + 2 * l);
      ypart[p] = vvp.x * k0 + vvp.y * k1;
      yp0 = fmaf(pl[p], vvp.x, yp0);
      yp1 = fmaf(pl[p], vvp.y, yp1);
    }
#pragma unroll
    for (int p = 0; p < P_; ++p) {
      float s = ypart[p];
#pragma unroll
      for (int off = 32; off; off >>= 1) s += __shfl_xor(s, off);
      ypart[p] = s;
    }
    float* op = out + (size_t)bn * (P_ * D_);
#pragma unroll
    for (int p = 0; p < P_; ++p) {
      float2 o;
      o.x = yp0 * ypart[p];
      o.y = yp1 * ypart[p];
      *(float2*)(op + p * 128 + 2 * l) = o;
    }
    __syncthreads();
  }
}

extern "C" void kernel_launch(void* const* d_in, const int* in_sizes, int n_in,
                              void* d_out, int out_size, void* d_ws, size_t ws_size,
                              hipStream_t stream) {
  const float* x   = (const float*)d_in[0];
  const float* wk  = (const float*)d_in[1];
  const float* kg  = (const float*)d_in[2];
  const float* kbb = (const float*)d_in[3];
  const float* krm = (const float*)d_in[4];
  const float* krv = (const float*)d_in[5];
  const float* wvp = (const float*)d_in[6];
  const float* vg  = (const float*)d_in[7];
  const float* vbb = (const float*)d_in[8];
  const float* vrm = (const float*)d_in[9];
  const float* vrv = (const float*)d_in[10];
  const float* wa1 = (const float*)d_in[11];
  const float* wa2 = (const float*)d_in[12];
  const float* wm1 = (const float*)d_in[13];
  const float* wm2 = (const float*)d_in[14];
  float* out = (float*)d_out;

  k1_pool<<<4096, 256, 0, stream>>>(x);
  k2_l1<<<192, 256, 0, stream>>>(wa1, wm1);
  k2_l2<<<192, 256, 0, stream>>>(wa2, wm2);
  k3_main<<<1024, 256, 0, stream>>>(x, wk, kg, kbb, krm, krv, wvp, vg, vbb, vrm, vrv, out);
}

// Round 2
// 107.849 us; speedup vs baseline: 1.1415x; 1.1415x over previous
//
#include <hip/hip_runtime.h>
#include <hip/hip_bf16.h>

#define B_   64
#define N_   256
#define P_   12
#define D_   128
#define BN_  (B_*N_)      // 16384
#define EPSV 1e-5f
#define VST  130          // padded v_l row stride (floats)

typedef float  f32x4  __attribute__((ext_vector_type(4)));
typedef __bf16 bf16x8 __attribute__((ext_vector_type(8)));
typedef __bf16 bf16x4 __attribute__((ext_vector_type(4)));

// module-scope scratch (fully rewritten every launch -> deterministic)
__device__ float g_avg[768*256];     // [b*12+p][n]  mean over d
__device__ float g_mx [768*256];     // [b*12+p][n]  max over d
__device__ float g_h1 [1536*128];    // rows 0..767 avg-branch, 768..1535 max-branch
__device__ float g_pool[BN_*P_];     // [bn][p] = sig(avg)+sig(max)

__device__ inline float sigm_(float x) { return 1.0f / (1.0f + __expf(-x)); }

__device__ inline float dot4_(float4 a, float4 b, float acc) {
  acc = fmaf(a.x, b.x, acc); acc = fmaf(a.y, b.y, acc);
  acc = fmaf(a.z, b.z, acc); acc = fmaf(a.w, b.w, acc);
  return acc;
}

// ---------------- K1: mean/max over d, one wave per (b,n) -------------------
// lane layout: half-wave handles one p-row; lane32 loads float4 -> 5-level reduce
__global__ __launch_bounds__(256) void k1_pool(const float* __restrict__ x) {
  int w = threadIdx.x >> 6, l = threadIdx.x & 63;
  int bn = blockIdx.x * 4 + w;
  const float* xp = x + (size_t)bn * (P_ * D_);
  int half = l >> 5, lane32 = l & 31;
  float s6[6], m6[6];
#pragma unroll
  for (int pp = 0; pp < 6; ++pp) {
    int p = pp * 2 + half;
    float4 v = *(const float4*)(xp + p * D_ + lane32 * 4);
    float s = (v.x + v.y) + (v.z + v.w);
    float m = fmaxf(fmaxf(v.x, v.y), fmaxf(v.z, v.w));
#pragma unroll
    for (int off = 16; off; off >>= 1) {
      s += __shfl_xor(s, off);
      m = fmaxf(m, __shfl_xor(m, off));
    }
    s6[pp] = s * (1.0f / D_);
    m6[pp] = m;
  }
  if (lane32 == 0) {
    int b = bn >> 8, n = bn & 255;
#pragma unroll
    for (int pp = 0; pp < 6; ++pp) {
      int p = pp * 2 + half;
      g_avg[(b * P_ + p) * N_ + n] = s6[pp];
      g_mx [(b * P_ + p) * N_ + n] = m6[pp];
    }
  }
}

// ---------------- K2a: layer1 (256->128) + exact GELU -----------------------
__global__ __launch_bounds__(256) void k2_l1(const float* __restrict__ w_avg1,
                                             const float* __restrict__ w_max1) {
  __shared__ float in_t[16 * 256];
  __shared__ float w_t[64 * 68];
  int t = threadIdx.x;
  int rblk = blockIdx.x % 96, cblk = blockIdx.x / 96;
  int rr0 = rblk * 16, c0 = cblk * 64;
  bool mxb = (rr0 >= 768);
  int r768 = mxb ? rr0 - 768 : rr0;
  const float* in = (mxb ? g_mx : g_avg) + (size_t)r768 * 256;
  const float* w1 = mxb ? w_max1 : w_avg1;
#pragma unroll
  for (int i = 0; i < 4; ++i) {
    int F = t + i * 256, r = F >> 6, k4 = F & 63;
    *(float4*)(in_t + r * 256 + k4 * 4) = *(const float4*)(in + r * 256 + k4 * 4);
  }
  int c = t & 63, rq = t >> 6;
  float a0 = 0, a1 = 0, a2 = 0, a3 = 0;
  for (int kc = 0; kc < 4; ++kc) {
    __syncthreads();
#pragma unroll
    for (int i = 0; i < 4; ++i) {
      int F = t + i * 256, cr = F >> 4, k4 = F & 15;
      *(float4*)(w_t + cr * 68 + k4 * 4) =
          *(const float4*)(w1 + (size_t)(c0 + cr) * 256 + kc * 64 + k4 * 4);
    }
    __syncthreads();
#pragma unroll
    for (int k4 = 0; k4 < 16; ++k4) {
      float4 wv4 = *(float4*)(w_t + c * 68 + k4 * 4);
      a0 = dot4_(*(float4*)(in_t + (rq * 4 + 0) * 256 + kc * 64 + k4 * 4), wv4, a0);
      a1 = dot4_(*(float4*)(in_t + (rq * 4 + 1) * 256 + kc * 64 + k4 * 4), wv4, a1);
      a2 = dot4_(*(float4*)(in_t + (rq * 4 + 2) * 256 + kc * 64 + k4 * 4), wv4, a2);
      a3 = dot4_(*(float4*)(in_t + (rq * 4 + 3) * 256 + kc * 64 + k4 * 4), wv4, a3);
    }
  }
  float accs[4] = {a0, a1, a2, a3};
#pragma unroll
  for (int r = 0; r < 4; ++r) {
    float a = accs[r];
    float g = 0.5f * a * (1.0f + erff(a * 0.70710678f));
    g_h1[(size_t)(rr0 + rq * 4 + r) * 128 + c0 + c] = g;
  }
}

// ---------------- K2b: layer2 (128->256), sigmoid, branch-sum ---------------
__global__ __launch_bounds__(256) void k2_l2(const float* __restrict__ w_avg2,
                                             const float* __restrict__ w_max2) {
  __shared__ float ina_t[16 * 128];
  __shared__ float inm_t[16 * 128];
  __shared__ float wa_t[64 * 68];
  __shared__ float wm_t[64 * 68];
  int t = threadIdx.x;
  int rblk = blockIdx.x % 48, cblk = blockIdx.x / 48;
  int rr0 = rblk * 16, n0 = cblk * 64;
#pragma unroll
  for (int i = 0; i < 2; ++i) {
    int F = t + i * 256, r = F >> 5, k4 = F & 31;
    *(float4*)(ina_t + r * 128 + k4 * 4) = *(const float4*)(g_h1 + (size_t)(rr0 + r) * 128 + k4 * 4);
    *(float4*)(inm_t + r * 128 + k4 * 4) = *(const float4*)(g_h1 + (size_t)(768 + rr0 + r) * 128 + k4 * 4);
  }
  int c = t & 63, rq = t >> 6;
  float aa0=0, aa1=0, aa2=0, aa3=0, am0=0, am1=0, am2=0, am3=0;
  for (int kc = 0; kc < 2; ++kc) {
    __syncthreads();
#pragma unroll
    for (int i = 0; i < 4; ++i) {
      int F = t + i * 256, cr = F >> 4, k4 = F & 15;
      *(float4*)(wa_t + cr * 68 + k4 * 4) =
          *(const float4*)(w_avg2 + (size_t)(n0 + cr) * 128 + kc * 64 + k4 * 4);
      *(float4*)(wm_t + cr * 68 + k4 * 4) =
          *(const float4*)(w_max2 + (size_t)(n0 + cr) * 128 + kc * 64 + k4 * 4);
    }
    __syncthreads();
#pragma unroll
    for (int k4 = 0; k4 < 16; ++k4) {
      float4 wa4 = *(float4*)(wa_t + c * 68 + k4 * 4);
      float4 wm4 = *(float4*)(wm_t + c * 68 + k4 * 4);
      float4 i0 = *(float4*)(ina_t + (rq * 4 + 0) * 128 + kc * 64 + k4 * 4);
      float4 i1 = *(float4*)(ina_t + (rq * 4 + 1) * 128 + kc * 64 + k4 * 4);
      float4 i2 = *(float4*)(ina_t + (rq * 4 + 2) * 128 + kc * 64 + k4 * 4);
      float4 i3 = *(float4*)(ina_t + (rq * 4 + 3) * 128 + kc * 64 + k4 * 4);
      aa0 = dot4_(i0, wa4, aa0); aa1 = dot4_(i1, wa4, aa1);
      aa2 = dot4_(i2, wa4, aa2); aa3 = dot4_(i3, wa4, aa3);
      float4 j0 = *(float4*)(inm_t + (rq * 4 + 0) * 128 + kc * 64 + k4 * 4);
      float4 j1 = *(float4*)(inm_t + (rq * 4 + 1) * 128 + kc * 64 + k4 * 4);
      float4 j2 = *(float4*)(inm_t + (rq * 4 + 2) * 128 + kc * 64 + k4 * 4);
      float4 j3 = *(float4*)(inm_t + (rq * 4 + 3) * 128 + kc * 64 + k4 * 4);
      am0 = dot4_(j0, wm4, am0); am1 = dot4_(j1, wm4, am1);
      am2 = dot4_(j2, wm4, am2); am3 = dot4_(j3, wm4, am3);
    }
  }
  float va[4] = {aa0, aa1, aa2, aa3};
  float vm[4] = {am0, am1, am2, am3};
#pragma unroll
  for (int r = 0; r < 4; ++r) {
    int rr = rr0 + rq * 4 + r;
    int b = rr / 12, p = rr % 12;
    float pv = sigm_(va[r]) + sigm_(vm[r]);
    g_pool[((size_t)b * 256 + (n0 + c)) * 12 + p] = pv;
  }
}

// ---------------- K3: fused main (k, v via MFMA, y, y_pool, out) ------------
// grid = 1024 blocks x 256 thr; each wave handles 4 bn sequentially.
// NO barriers inside the loop: v_l is strictly per-wave; wv_lds is read-only
// after the single post-staging barrier.
__global__ __launch_bounds__(256) void k3_main(
    const float* __restrict__ x,  const float* __restrict__ wk,
    const float* __restrict__ kg, const float* __restrict__ kb,
    const float* __restrict__ krm, const float* __restrict__ krv,
    const float* __restrict__ wv,
    const float* __restrict__ vg, const float* __restrict__ vb,
    const float* __restrict__ vrm, const float* __restrict__ vrv,
    float* __restrict__ out) {
  __shared__ __align__(16) __bf16 wv_lds[128 * 128];  // [e][d] bf16, *sv[e], XOR-swizzled
  __shared__ float sv_l[128], tv_l[128];
  __shared__ float v_l[4][P_ * VST];   // padded stride: bank-conflict-free epilogue

  int t = threadIdx.x, w = t >> 6, l = t & 63;
  if (t < 128) {
    float s = vg[t] * rsqrtf(vrv[t] + EPSV);
    sv_l[t] = s;
    tv_l[t] = vb[t] - vrm[t] * s;
  }
  __syncthreads();
  {
    int e = t >> 1, dh = (t & 1) * 64;
    float s = sv_l[e];
    int swz = (e & 7) << 4;
#pragma unroll
    for (int i = 0; i < 16; ++i) {
      float4 v4 = *(const float4*)(wv + (size_t)e * 128 + dh + i * 4);
      bf16x4 h;
      h[0] = (__bf16)(v4.x * s); h[1] = (__bf16)(v4.y * s);
      h[2] = (__bf16)(v4.z * s); h[3] = (__bf16)(v4.w * s);
      int byte = (e * 256 + (dh + i * 4) * 2) ^ swz;
      *(bf16x4*)((char*)wv_lds + byte) = h;
    }
  }
  float ksc = kg[0] * rsqrtf(krv[0] + EPSV);
  float kbs = kb[0] - krm[0] * ksc;
  __syncthreads();   // wv_lds ready; read-only from here on

  int arow = (l & 15) > 11 ? 11 : (l & 15);  // clamp pad rows
  int ak = (l >> 4) * 8;
  int bcol = l & 15;
  int bko = (l >> 4) * 16;
  float* vw = &v_l[w][0];

  for (int it = 0; it < 4; ++it) {
    int bn = blockIdx.x * 16 + it * 4 + w;
    const float* xp = x + (size_t)bn * (P_ * D_);

    // hoist g_pool load: latency hides under MFMA
    const float* pp = g_pool + (size_t)bn * 12;
    float pl[P_];
#pragma unroll
    for (int p = 0; p < P_; ++p) pl[p] = pp[p];

    // A fragments: fp32 global -> bf16, 8 contiguous k per lane
    bf16x8 afr[4];
#pragma unroll
    for (int ks = 0; ks < 4; ++ks) {
      const float* src = xp + arow * 128 + ks * 32 + ak;
      float4 lo = *(const float4*)(src);
      float4 hi = *(const float4*)(src + 4);
      bf16x8 a;
      a[0] = (__bf16)lo.x; a[1] = (__bf16)lo.y; a[2] = (__bf16)lo.z; a[3] = (__bf16)lo.w;
      a[4] = (__bf16)hi.x; a[5] = (__bf16)hi.y; a[6] = (__bf16)hi.z; a[7] = (__bf16)hi.w;
      afr[ks] = a;
    }

    // k branch: k_raw over p, BN(1ch), SiLU, softmax over d (2 elems/lane)
    float kr0 = 0, kr1 = 0;
#pragma unroll
    for (int p = 0; p < P_; ++p) {
      float2 xv = *(const float2*)(xp + p * 128 + 2 * l);
      float wkp = wk[p];
      kr0 = fmaf(xv.x, wkp, kr0);
      kr1 = fmaf(xv.y, wkp, kr1);
    }
    float z0 = kr0 * ksc + kbs, z1 = kr1 * ksc + kbs;
    z0 = z0 * sigm_(z0);
    z1 = z1 * sigm_(z1);
    float mmax = fmaxf(z0, z1);
#pragma unroll
    for (int off = 32; off; off >>= 1) mmax = fmaxf(mmax, __shfl_xor(mmax, off));
    float e0 = __expf(z0 - mmax), e1 = __expf(z1 - mmax);
    float es = e0 + e1;
#pragma unroll
    for (int off = 32; off; off >>= 1) es += __shfl_xor(es, off);
    float inv = 1.0f / es;
    float k0 = e0 * inv, k1 = e1 * inv;

    // v_raw = xf @ (wv*sv)^T via MFMA 16x16x32 bf16
    f32x4 acc[8];
#pragma unroll
    for (int nt = 0; nt < 8; ++nt) acc[nt] = (f32x4){0.f, 0.f, 0.f, 0.f};
#pragma unroll
    for (int nt = 0; nt < 8; ++nt) {
      int er = bcol + nt * 16;
      int base = er * 256;
      int sw = (er & 7) << 4;
#pragma unroll
      for (int ks = 0; ks < 4; ++ks) {
        int byte = (base + ks * 64 + bko) ^ sw;
        bf16x8 bfr = *(const bf16x8*)((const char*)wv_lds + byte);
        acc[nt] = __builtin_amdgcn_mfma_f32_16x16x32_bf16(afr[ks], bfr, acc[nt], 0, 0, 0);
      }
    }

    // epilogue: + tv[e], SiLU, stash v tile in per-wave LDS (rows 12..15 dropped)
    int p0 = (l >> 4) * 4;
    if (p0 < 12) {
#pragma unroll
      for (int nt = 0; nt < 8; ++nt) {
        int e = bcol + nt * 16;
        float tvv = tv_l[e];
#pragma unroll
        for (int r = 0; r < 4; ++r) {
          float a = acc[nt][r] + tvv;
          float v = a * sigm_(a);
          vw[(p0 + r) * VST + e] = v;
        }
      }
    }
    // same-wave LDS write->read: compiler inserts lgkmcnt wait; no barrier needed

    // y[p] = sum_e v*k ; y_pool[e] = sum_p pool*v ; out = y_pool (x) y
    float yp0 = 0, yp1 = 0;
    float ypart[P_];
#pragma unroll
    for (int p = 0; p < P_; ++p) {
      float2 vvp = *(const float2*)(vw + p * VST + 2 * l);
      ypart[p] = vvp.x * k0 + vvp.y * k1;
      yp0 = fmaf(pl[p], vvp.x, yp0);
      yp1 = fmaf(pl[p], vvp.y, yp1);
    }
#pragma unroll
    for (int p = 0; p < P_; ++p) {
      float s = ypart[p];
#pragma unroll
      for (int off = 32; off; off >>= 1) s += __shfl_xor(s, off);
      ypart[p] = s;
    }
    float* op = out + (size_t)bn * (P_ * D_);
#pragma unroll
    for (int p = 0; p < P_; ++p) {
      float2 o;
      o.x = yp0 * ypart[p];
      o.y = yp1 * ypart[p];
      *(float2*)(op + p * 128 + 2 * l) = o;
    }
  }
}

extern "C" void kernel_launch(void* const* d_in, const int* in_sizes, int n_in,
                              void* d_out, int out_size, void* d_ws, size_t ws_size,
                              hipStream_t stream) {
  const float* x   = (const float*)d_in[0];
  const float* wk  = (const float*)d_in[1];
  const float* kg  = (const float*)d_in[2];
  const float* kbb = (const float*)d_in[3];
  const float* krm = (const float*)d_in[4];
  const float* krv = (const float*)d_in[5];
  const float* wvp = (const float*)d_in[6];
  const float* vg  = (const float*)d_in[7];
  const float* vbb = (const float*)d_in[8];
  const float* vrm = (const float*)d_in[9];
  const float* vrv = (const float*)d_in[10];
  const float* wa1 = (const float*)d_in[11];
  const float* wa2 = (const float*)d_in[12];
  const float* wm1 = (const float*)d_in[13];
  const float* wm2 = (const float*)d_in[14];
  float* out = (float*)d_out;

  k1_pool<<<4096, 256, 0, stream>>>(x);
  k2_l1<<<192, 256, 0, stream>>>(wa1, wm1);
  k2_l2<<<192, 256, 0, stream>>>(wa2, wm2);
  k3_main<<<1024, 256, 0, stream>>>(x, wk, kg, kbb, krm, krv, wvp, vg, vbb, vrm, vrv, out);
}